// Round 4
// baseline (971.441 us; speedup 1.0000x reference)
//
#include <hip/hip_runtime.h>
#include <hip/hip_bf16.h>

#define N_TOK 4096
#define DIM   1024
#define HID   4096
#define NE    8
#define ROW_CAP128 13312   // 128-aligned expert regions (<=9216) + 4096 shared
#define ROW_CAP64  12800   // fallback path (64-aligned)

typedef unsigned short ushort_t;
typedef short bf16x8 __attribute__((ext_vector_type(8)));
typedef float f32x4 __attribute__((ext_vector_type(4)));

// ---------- helpers ----------
__device__ __forceinline__ ushort_t f2bf(float f) {
    unsigned int u = __float_as_uint(f);
    u += 0x7fffu + ((u >> 16) & 1u);          // round-to-nearest-even
    return (ushort_t)(u >> 16);
}
__device__ __forceinline__ float bf2f(ushort_t u) {
    return __uint_as_float(((unsigned int)u) << 16);
}
__device__ __forceinline__ float gelu_f(float v) {
    return 0.5f * v * (1.0f + erff(v * 0.70710678118654752f));
}
// raw exec-barrier: no vmcnt drain (in-flight global prefetch loads stay in flight).
// lgkm-only wait (vmcnt=63, expcnt=7, lgkmcnt=0 -> 0xC07F) for safety; usually already 0.
__device__ __forceinline__ void barrier_novm() {
    __builtin_amdgcn_s_waitcnt(0xC07F);
    __builtin_amdgcn_s_barrier();
}
__device__ __forceinline__ void fma4x4(const float4& a, const float4& b, float acc[4][4]) {
    acc[0][0] = fmaf(a.x, b.x, acc[0][0]); acc[0][1] = fmaf(a.x, b.y, acc[0][1]);
    acc[0][2] = fmaf(a.x, b.z, acc[0][2]); acc[0][3] = fmaf(a.x, b.w, acc[0][3]);
    acc[1][0] = fmaf(a.y, b.x, acc[1][0]); acc[1][1] = fmaf(a.y, b.y, acc[1][1]);
    acc[1][2] = fmaf(a.y, b.z, acc[1][2]); acc[1][3] = fmaf(a.y, b.w, acc[1][3]);
    acc[2][0] = fmaf(a.z, b.x, acc[2][0]); acc[2][1] = fmaf(a.z, b.y, acc[2][1]);
    acc[2][2] = fmaf(a.z, b.z, acc[2][2]); acc[2][3] = fmaf(a.z, b.w, acc[2][3]);
    acc[3][0] = fmaf(a.w, b.x, acc[3][0]); acc[3][1] = fmaf(a.w, b.y, acc[3][1]);
    acc[3][2] = fmaf(a.w, b.z, acc[3][2]); acc[3][3] = fmaf(a.w, b.w, acc[3][3]);
}

// ---------- gating ----------
__global__ __launch_bounds__(256) void gate_kernel(
    const float* __restrict__ x, const float* __restrict__ gw, const float* __restrict__ gb,
    int* __restrict__ counts, float* __restrict__ importance,
    int* __restrict__ sel, float* __restrict__ selw)
{
    __shared__ float s_imp[NE];
    __shared__ int   s_cnt[NE];
    int tid = threadIdx.x;
    if (tid < NE) { s_imp[tid] = 0.f; s_cnt[tid] = 0; }
    __syncthreads();

    int wave = tid >> 6, lane = tid & 63;
    int n = blockIdx.x * 4 + wave;

    float acc[NE];
#pragma unroll
    for (int e = 0; e < NE; ++e) acc[e] = 0.f;

    const float* xr = x + (size_t)n * DIM;
    for (int it = 0; it < DIM / 64; ++it) {
        int d = it * 64 + lane;
        float xv = xr[d];
        const float4* g = (const float4*)(gw + (size_t)d * NE);
        float4 g0 = g[0], g1 = g[1];
        acc[0] = fmaf(xv, g0.x, acc[0]); acc[1] = fmaf(xv, g0.y, acc[1]);
        acc[2] = fmaf(xv, g0.z, acc[2]); acc[3] = fmaf(xv, g0.w, acc[3]);
        acc[4] = fmaf(xv, g1.x, acc[4]); acc[5] = fmaf(xv, g1.y, acc[5]);
        acc[6] = fmaf(xv, g1.z, acc[6]); acc[7] = fmaf(xv, g1.w, acc[7]);
    }
#pragma unroll
    for (int off = 32; off > 0; off >>= 1) {
#pragma unroll
        for (int e = 0; e < NE; ++e) acc[e] += __shfl_down(acc[e], off, 64);
    }

    if (lane == 0) {
        float lg[NE], p[NE];
        float mx = -1e30f;
#pragma unroll
        for (int e = 0; e < NE; ++e) { lg[e] = acc[e] + gb[e]; mx = fmaxf(mx, lg[e]); }
        float se = 0.f;
#pragma unroll
        for (int e = 0; e < NE; ++e) { p[e] = expf(lg[e] - mx); se += p[e]; }
        float inv = 1.f / se;
#pragma unroll
        for (int e = 0; e < NE; ++e) atomicAdd(&s_imp[e], p[e] * inv);
        int i1 = 0;
#pragma unroll
        for (int e = 1; e < NE; ++e) if (lg[e] > lg[i1]) i1 = e;
        int i2 = -1;
#pragma unroll
        for (int e = 0; e < NE; ++e) if (e != i1 && (i2 < 0 || lg[e] > lg[i2])) i2 = e;
        float t = expf(lg[i2] - lg[i1]);
        float wA = 1.f / (1.f + t), wB = t / (1.f + t);
        sel[n * 2] = i1; sel[n * 2 + 1] = i2;
        selw[n * 2] = wA; selw[n * 2 + 1] = wB;
        atomicAdd(&s_cnt[i1], 1); atomicAdd(&s_cnt[i2], 1);
    }
    __syncthreads();
    if (tid < NE) {
        atomicAdd(&importance[tid], s_imp[tid]);
        atomicAdd(&counts[tid], s_cnt[tid]);
    }
}

// ---------- plan ----------
__global__ void plan_kernel(
    const int* __restrict__ counts, const float* __restrict__ importance,
    int* __restrict__ cursors, int* __restrict__ offs, int* __restrict__ total_rows,
    int* __restrict__ row_token, float* __restrict__ row_wt, float* __restrict__ out_aux,
    int al)
{
    __shared__ int s_offs[NE + 1], s_cnt[NE];
    if (threadIdx.x == 0) {
        int o = 0;
        for (int e = 0; e < NE; ++e) {
            s_cnt[e] = counts[e];
            s_offs[e] = o;
            cursors[e] = o;
            o += (s_cnt[e] + al - 1) & ~(al - 1);
        }
        s_offs[NE] = o;
        for (int e = 0; e <= NE; ++e) offs[e] = s_offs[e];
        *total_rows = o + N_TOK;
        float is = 1e-8f, ls = 1e-8f;
        for (int e = 0; e < NE; ++e) { is += importance[e]; ls += (float)s_cnt[e]; }
        float aux = 0.f;
        for (int e = 0; e < NE; ++e) {
            float d = importance[e] / is - (float)s_cnt[e] / ls;
            aux += d * d;
        }
        *out_aux = aux;
    }
    __syncthreads();
    for (int e = 0; e < NE; ++e) {
        int st = s_offs[e] + s_cnt[e], en = s_offs[e + 1];
        for (int i = st + (int)threadIdx.x; i < en; i += (int)blockDim.x) {
            row_token[i] = -1; row_wt[i] = 0.f;
        }
    }
}

// ---------- scatter ----------
__global__ __launch_bounds__(256) void scatter_kernel(
    const int* __restrict__ sel, const float* __restrict__ selw,
    int* __restrict__ cursors, const int* __restrict__ offs,
    int* __restrict__ row_token, float* __restrict__ row_wt)
{
    int n = blockIdx.x * 256 + threadIdx.x;
#pragma unroll
    for (int k = 0; k < 2; ++k) {
        int e = sel[n * 2 + k];
        int pos = atomicAdd(&cursors[e], 1);
        row_token[pos] = n;
        row_wt[pos] = selw[n * 2 + k];
    }
    int off8 = offs[NE];
    row_token[off8 + n] = n;
    row_wt[off8 + n] = 1.0f;
}

// ---------- fp32 x -> bf16 ----------
__global__ __launch_bounds__(256) void cvt_x_kernel(
    const float* __restrict__ x, ushort_t* __restrict__ xb)
{
    int i = (blockIdx.x * 256 + threadIdx.x) * 8;
    float4 a = *(const float4*)(x + i);
    float4 b = *(const float4*)(x + i + 4);
    uint4 o;
    o.x = ((unsigned)f2bf(a.y) << 16) | f2bf(a.x);
    o.y = ((unsigned)f2bf(a.w) << 16) | f2bf(a.z);
    o.z = ((unsigned)f2bf(b.y) << 16) | f2bf(b.x);
    o.w = ((unsigned)f2bf(b.w) << 16) | f2bf(b.z);
    *(uint4*)(xb + i) = o;
}

// ---------- transpose+convert: src [K][N] fp32 -> dst [N][K] bf16 ----------
// z in [0,9): z<8 -> experts from src; z==8 -> shared weights from srcS
__global__ __launch_bounds__(256) void transpose_bf16(
    const float* __restrict__ src, const float* __restrict__ srcS,
    ushort_t* __restrict__ dst, int K, int N)
{
    __shared__ ushort_t T[64][80];
    const float* s = (blockIdx.z < 8) ? (src + (size_t)blockIdx.z * K * N) : srcS;
    dst += (size_t)blockIdx.z * K * N;
    int n0 = blockIdx.x * 64, k0 = blockIdx.y * 64;
    int t = threadIdx.x;
    int cq = (t & 15) * 4;
    int kr = t >> 4;
#pragma unroll
    for (int rI = 0; rI < 4; ++rI) {
        int k = kr + rI * 16;
        float4 v = *(const float4*)(s + (size_t)(k0 + k) * N + n0 + cq);
        T[cq + 0][k] = f2bf(v.x);
        T[cq + 1][k] = f2bf(v.y);
        T[cq + 2][k] = f2bf(v.z);
        T[cq + 3][k] = f2bf(v.w);
    }
    __syncthreads();
    int nr = t >> 2;
    int kq = (t & 3) * 16;
    uint4 o0 = *(const uint4*)&T[nr][kq];
    uint4 o1 = *(const uint4*)&T[nr][kq + 8];
    ushort_t* dp = dst + (size_t)(n0 + nr) * K + k0 + kq;
    *(uint4*)dp = o0;
    *(uint4*)(dp + 8) = o1;
}

// ---------- MFMA grouped GEMM, layer 1: hbuf = gelu(Xg @ W1_e + b1_e) ----------
// grid: (x = col tiles [32], y = row tiles [104]) — col-fastest for L2/L3 locality
// K-loop: register-prefetch pipeline (loads for iter i+1 in flight across barrier-2)
__global__ __launch_bounds__(256) void ffn1_mfma(
    const ushort_t* __restrict__ xb, const ushort_t* __restrict__ wtbuf,
    const float* __restrict__ b1, const float* __restrict__ sb1,
    const int* __restrict__ offs, const int* __restrict__ total_rows,
    const int* __restrict__ row_token, ushort_t* __restrict__ hbuf)
{
    const int row0 = blockIdx.y * 128;
    if (row0 >= *total_rows) return;
    const int col0 = blockIdx.x * 128;

    int e = 0;
#pragma unroll
    for (int i = 0; i < NE; ++i) e += (row0 >= offs[i + 1]) ? 1 : 0;
    const ushort_t* W = wtbuf + (size_t)e * (HID * DIM);       // [HID][DIM] bf16
    const float* Bv = (e < NE) ? (b1 + (size_t)e * HID) : sb1;

    __shared__ ushort_t As[4096];   // 8 slabs x 512 ushort (lane-ordered, 16B/lane)
    __shared__ ushort_t Bs[4096];

    const int tid = threadIdx.x;
    const int lane = tid & 63;
    const int w = tid >> 6;
    const int wm = w & 1, wn = w >> 1;
    const int lm = lane & 15, lk = lane >> 4;

    const int sS = 2 * w;
    int r0 = row0 + (sS + 0) * 16 + lm;
    int r1 = row0 + (sS + 1) * 16 + lm;
    int t0 = row_token[r0]; if (t0 < 0) t0 = 0;
    int t1 = row_token[r1]; if (t1 < 0) t1 = 0;
    const ushort_t* gA0 = xb + (size_t)t0 * DIM + lk * 8;
    const ushort_t* gA1 = xb + (size_t)t1 * DIM + lk * 8;
    const ushort_t* gB0 = W + (size_t)(col0 + (sS + 0) * 16 + lm) * DIM + lk * 8;
    const ushort_t* gB1 = W + (size_t)(col0 + (sS + 1) * 16 + lm) * DIM + lk * 8;
    ushort_t* lA0 = &As[(sS + 0) * 512 + lane * 8];
    ushort_t* lA1 = &As[(sS + 1) * 512 + lane * 8];
    ushort_t* lB0 = &Bs[(sS + 0) * 512 + lane * 8];
    ushort_t* lB1 = &Bs[(sS + 1) * 512 + lane * 8];

    f32x4 zero = {0.f, 0.f, 0.f, 0.f};
    f32x4 acc[4][4];
#pragma unroll
    for (int i = 0; i < 4; ++i)
#pragma unroll
        for (int j = 0; j < 4; ++j) acc[i][j] = zero;

    const bf16x8* Af = (const bf16x8*)As;
    const bf16x8* Bf = (const bf16x8*)Bs;

    // prologue: prefetch k0 = 0
    uint4 rA0 = *(const uint4*)(gA0);
    uint4 rA1 = *(const uint4*)(gA1);
    uint4 rB0 = *(const uint4*)(gB0);
    uint4 rB1 = *(const uint4*)(gB1);

    for (int k0 = 0; k0 < DIM; k0 += 32) {
        // stage prefetched regs -> LDS (vmcnt wait lands here)
        *(uint4*)lA0 = rA0;
        *(uint4*)lA1 = rA1;
        *(uint4*)lB0 = rB0;
        *(uint4*)lB1 = rB1;
        __syncthreads();                       // lgkm drain; vmcnt already 0
        // issue next iteration's loads (in flight through MFMA phase + barrier-2)
        if (k0 + 32 < DIM) {
            rA0 = *(const uint4*)(gA0 + k0 + 32);
            rA1 = *(const uint4*)(gA1 + k0 + 32);
            rB0 = *(const uint4*)(gB0 + k0 + 32);
            rB1 = *(const uint4*)(gB1 + k0 + 32);
        }
        bf16x8 a[4], b[4];
#pragma unroll
        for (int i = 0; i < 4; ++i) a[i] = Af[(wm * 4 + i) * 64 + lane];
#pragma unroll
        for (int j = 0; j < 4; ++j) b[j] = Bf[(wn * 4 + j) * 64 + lane];
#pragma unroll
        for (int i = 0; i < 4; ++i)
#pragma unroll
            for (int j = 0; j < 4; ++j)
                acc[i][j] = __builtin_amdgcn_mfma_f32_16x16x32_bf16(a[i], b[j], acc[i][j], 0, 0, 0);
        barrier_novm();                        // exec-only: don't drain prefetch loads
    }

#pragma unroll
    for (int j = 0; j < 4; ++j) {
        int C = col0 + (wn * 4 + j) * 16 + lm;
        float bj = Bv[C];
#pragma unroll
        for (int i = 0; i < 4; ++i) {
            int Rb = row0 + (wm * 4 + i) * 16 + lk * 4;
#pragma unroll
            for (int r = 0; r < 4; ++r) {
                float v = gelu_f(acc[i][j][r] + bj);
                hbuf[(size_t)(Rb + r) * HID + C] = f2bf(v);
            }
        }
    }
}

// ---------- MFMA grouped GEMM, layer 2: out[tok] += wt*(hbuf @ W2_e + b2_e) ----------
// grid: (x = col tiles [8], y = row tiles [104])
__global__ __launch_bounds__(256) void ffn2_mfma(
    const ushort_t* __restrict__ hbuf, const ushort_t* __restrict__ wtbuf,
    const float* __restrict__ b2, const float* __restrict__ sb2,
    const int* __restrict__ offs, const int* __restrict__ total_rows,
    const int* __restrict__ row_token, const float* __restrict__ row_wt,
    float* __restrict__ out)
{
    const int row0 = blockIdx.y * 128;
    if (row0 >= *total_rows) return;
    const int col0 = blockIdx.x * 128;

    int e = 0;
#pragma unroll
    for (int i = 0; i < NE; ++i) e += (row0 >= offs[i + 1]) ? 1 : 0;
    const ushort_t* W = wtbuf + (size_t)e * (HID * DIM);       // [DIM][HID] bf16
    const float* Bv = (e < NE) ? (b2 + (size_t)e * DIM) : sb2;

    __shared__ ushort_t As[4096];
    __shared__ ushort_t Bs[4096];
    __shared__ int   s_tok[128];
    __shared__ float s_wt[128];

    const int tid = threadIdx.x;
    if (tid < 128) { s_tok[tid] = row_token[row0 + tid]; s_wt[tid] = row_wt[row0 + tid]; }

    const int lane = tid & 63;
    const int w = tid >> 6;
    const int wm = w & 1, wn = w >> 1;
    const int lm = lane & 15, lk = lane >> 4;

    const int sS = 2 * w;
    const ushort_t* gA0 = hbuf + (size_t)(row0 + (sS + 0) * 16 + lm) * HID + lk * 8;
    const ushort_t* gA1 = hbuf + (size_t)(row0 + (sS + 1) * 16 + lm) * HID + lk * 8;
    const ushort_t* gB0 = W + (size_t)(col0 + (sS + 0) * 16 + lm) * HID + lk * 8;
    const ushort_t* gB1 = W + (size_t)(col0 + (sS + 1) * 16 + lm) * HID + lk * 8;
    ushort_t* lA0 = &As[(sS + 0) * 512 + lane * 8];
    ushort_t* lA1 = &As[(sS + 1) * 512 + lane * 8];
    ushort_t* lB0 = &Bs[(sS + 0) * 512 + lane * 8];
    ushort_t* lB1 = &Bs[(sS + 1) * 512 + lane * 8];

    f32x4 zero = {0.f, 0.f, 0.f, 0.f};
    f32x4 acc[4][4];
#pragma unroll
    for (int i = 0; i < 4; ++i)
#pragma unroll
        for (int j = 0; j < 4; ++j) acc[i][j] = zero;

    const bf16x8* Af = (const bf16x8*)As;
    const bf16x8* Bf = (const bf16x8*)Bs;

    uint4 rA0 = *(const uint4*)(gA0);
    uint4 rA1 = *(const uint4*)(gA1);
    uint4 rB0 = *(const uint4*)(gB0);
    uint4 rB1 = *(const uint4*)(gB1);

    for (int k0 = 0; k0 < HID; k0 += 32) {
        *(uint4*)lA0 = rA0;
        *(uint4*)lA1 = rA1;
        *(uint4*)lB0 = rB0;
        *(uint4*)lB1 = rB1;
        __syncthreads();
        if (k0 + 32 < HID) {
            rA0 = *(const uint4*)(gA0 + k0 + 32);
            rA1 = *(const uint4*)(gA1 + k0 + 32);
            rB0 = *(const uint4*)(gB0 + k0 + 32);
            rB1 = *(const uint4*)(gB1 + k0 + 32);
        }
        bf16x8 a[4], b[4];
#pragma unroll
        for (int i = 0; i < 4; ++i) a[i] = Af[(wm * 4 + i) * 64 + lane];
#pragma unroll
        for (int j = 0; j < 4; ++j) b[j] = Bf[(wn * 4 + j) * 64 + lane];
#pragma unroll
        for (int i = 0; i < 4; ++i)
#pragma unroll
            for (int j = 0; j < 4; ++j)
                acc[i][j] = __builtin_amdgcn_mfma_f32_16x16x32_bf16(a[i], b[j], acc[i][j], 0, 0, 0);
        barrier_novm();
    }

#pragma unroll
    for (int j = 0; j < 4; ++j) {
        int C = col0 + (wn * 4 + j) * 16 + lm;
        float bj = Bv[C];
#pragma unroll
        for (int i = 0; i < 4; ++i) {
            int rb = (wm * 4 + i) * 16 + lk * 4;
#pragma unroll
            for (int r = 0; r < 4; ++r) {
                int tok = s_tok[rb + r];
                if (tok < 0) continue;
                float v = s_wt[rb + r] * (acc[i][j][r] + bj);
                atomicAdd(&out[(size_t)tok * DIM + C], v);
            }
        }
    }
}

// ---------- fallback fp32 FFN kernels (round-1, used only if ws too small) ----------
__global__ __launch_bounds__(256) void ffn1_kernel(
    const float* __restrict__ x, const float* __restrict__ w1, const float* __restrict__ b1,
    const float* __restrict__ sw1, const float* __restrict__ sb1,
    const int* __restrict__ offs, const int* __restrict__ total_rows,
    const int* __restrict__ row_token, ushort_t* __restrict__ hbuf)
{
    int row0 = blockIdx.x * 64;
    if (row0 >= *total_rows) return;
    int col0 = blockIdx.y * 64;
    int e = 0;
#pragma unroll
    for (int i = 1; i <= NE; ++i) if (row0 >= offs[i]) e = i;
    const float* W = (e < NE) ? w1 + (size_t)e * DIM * HID : sw1;
    const float* B = (e < NE) ? b1 + (size_t)e * HID : sb1;

    __shared__ float As_[16][68];
    __shared__ float Bs_[16][64];
    __shared__ int toks[64];
    int tid = threadIdx.x;
    if (tid < 64) toks[tid] = row_token[row0 + tid];
    __syncthreads();

    int am = tid >> 2, ak = (tid & 3) << 2;
    int bkr = tid >> 4, bn = (tid & 15) << 2;
    int tx = tid & 15, ty = tid >> 4;
    int tok = toks[am];
    const float* ap = x + (size_t)(tok >= 0 ? tok : 0) * DIM + ak;
    const float* bp = W + (size_t)bkr * HID + col0 + bn;

    float acc[4][4] = {};
    for (int k0 = 0; k0 < DIM; k0 += 16) {
        float4 av = make_float4(0.f, 0.f, 0.f, 0.f);
        if (tok >= 0) av = *(const float4*)(ap + k0);
        float4 bv = *(const float4*)(bp + (size_t)k0 * HID);
        As_[ak + 0][am] = av.x; As_[ak + 1][am] = av.y;
        As_[ak + 2][am] = av.z; As_[ak + 3][am] = av.w;
        *(float4*)&Bs_[bkr][bn] = bv;
        __syncthreads();
#pragma unroll
        for (int kk = 0; kk < 16; ++kk) {
            float4 a = *(const float4*)&As_[kk][ty * 4];
            float4 b = *(const float4*)&Bs_[kk][tx * 4];
            fma4x4(a, b, acc);
        }
        __syncthreads();
    }
    float4 bb = *(const float4*)(B + col0 + tx * 4);
    ushort_t* hp = hbuf + (size_t)(row0 + ty * 4) * HID + col0 + tx * 4;
#pragma unroll
    for (int r = 0; r < 4; ++r) {
        ushort4 pk;
        pk.x = f2bf(gelu_f(acc[r][0] + bb.x));
        pk.y = f2bf(gelu_f(acc[r][1] + bb.y));
        pk.z = f2bf(gelu_f(acc[r][2] + bb.z));
        pk.w = f2bf(gelu_f(acc[r][3] + bb.w));
        *(ushort4*)(hp + (size_t)r * HID) = pk;
    }
}

__global__ __launch_bounds__(256) void ffn2_kernel(
    const ushort_t* __restrict__ hbuf,
    const float* __restrict__ w2, const float* __restrict__ b2,
    const float* __restrict__ sw2, const float* __restrict__ sb2,
    const int* __restrict__ offs, const int* __restrict__ total_rows,
    const int* __restrict__ row_token, const float* __restrict__ row_wt,
    float* __restrict__ out)
{
    int row0 = blockIdx.x * 64;
    if (row0 >= *total_rows) return;
    int col0 = blockIdx.y * 64;
    int e = 0;
#pragma unroll
    for (int i = 1; i <= NE; ++i) if (row0 >= offs[i]) e = i;
    const float* W = (e < NE) ? w2 + (size_t)e * HID * DIM : sw2;
    const float* B = (e < NE) ? b2 + (size_t)e * DIM : sb2;

    __shared__ float As_[16][68];
    __shared__ float Bs_[16][64];
    __shared__ int toks[64];
    __shared__ float wts[64];
    int tid = threadIdx.x;
    if (tid < 64) { toks[tid] = row_token[row0 + tid]; wts[tid] = row_wt[row0 + tid]; }
    __syncthreads();

    int am = tid >> 2, ak = (tid & 3) << 2;
    int bkr = tid >> 4, bn = (tid & 15) << 2;
    int tx = tid & 15, ty = tid >> 4;
    const ushort_t* ap = hbuf + (size_t)(row0 + am) * HID + ak;
    const float* bp = W + (size_t)bkr * DIM + col0 + bn;

    float acc[4][4] = {};
    for (int k0 = 0; k0 < HID; k0 += 16) {
        ushort4 hv = *(const ushort4*)(ap + k0);
        float4 bv = *(const float4*)(bp + (size_t)k0 * DIM);
        As_[ak + 0][am] = bf2f(hv.x); As_[ak + 1][am] = bf2f(hv.y);
        As_[ak + 2][am] = bf2f(hv.z); As_[ak + 3][am] = bf2f(hv.w);
        *(float4*)&Bs_[bkr][bn] = bv;
        __syncthreads();
#pragma unroll
        for (int kk = 0; kk < 16; ++kk) {
            float4 a = *(const float4*)&As_[kk][ty * 4];
            float4 b = *(const float4*)&Bs_[kk][tx * 4];
            fma4x4(a, b, acc);
        }
        __syncthreads();
    }
    float4 bb = *(const float4*)(B + col0 + tx * 4);
#pragma unroll
    for (int r = 0; r < 4; ++r) {
        int rr = ty * 4 + r;
        int tok = toks[rr];
        if (tok < 0) continue;
        float w = wts[rr];
        float* op = out + (size_t)tok * DIM + col0 + tx * 4;
        atomicAdd(&op[0], w * (acc[r][0] + bb.x));
        atomicAdd(&op[1], w * (acc[r][1] + bb.y));
        atomicAdd(&op[2], w * (acc[r][2] + bb.z));
        atomicAdd(&op[3], w * (acc[r][3] + bb.w));
    }
}

// ---------- launch ----------
extern "C" void kernel_launch(void* const* d_in, const int* in_sizes, int n_in,
                              void* d_out, int out_size, void* d_ws, size_t ws_size,
                              hipStream_t stream)
{
    const float* x   = (const float*)d_in[0];
    const float* gw  = (const float*)d_in[1];
    const float* gb  = (const float*)d_in[2];
    const float* w1  = (const float*)d_in[3];
    const float* b1  = (const float*)d_in[4];
    const float* w2  = (const float*)d_in[5];
    const float* b2  = (const float*)d_in[6];
    const float* sw1 = (const float*)d_in[7];
    const float* sb1 = (const float*)d_in[8];
    const float* sw2 = (const float*)d_in[9];
    const float* sb2 = (const float*)d_in[10];
    float* out = (float*)d_out;

    char* ws = (char*)d_ws;
    int*   counts     = (int*)(ws + 0);
    int*   cursors    = (int*)(ws + 32);
    int*   offs       = (int*)(ws + 64);
    int*   total_rows = (int*)(ws + 100);
    float* importance = (float*)(ws + 128);
    int*   sel        = (int*)(ws + 256);
    float* selw       = (float*)(ws + 33024);
    int*   row_token  = (int*)(ws + 65792);
    float* row_wt     = (float*)(ws + 119040);

    const size_t XB_OFF = 262144;
    const size_t WT_OFF = XB_OFF + (size_t)N_TOK * DIM * 2;                 // 8.39 MB xb
    const size_t HB_OFF = WT_OFF + (size_t)9 * HID * DIM * 2;               // 75.5 MB weights
    const size_t NEED   = HB_OFF + (size_t)ROW_CAP128 * HID * 2;            // 109 MB hbuf
    ushort_t* xb    = (ushort_t*)(ws + XB_OFF);
    ushort_t* wtbuf = (ushort_t*)(ws + WT_OFF);

    hipMemsetAsync(d_out, 0, (size_t)out_size * sizeof(float), stream);
    hipMemsetAsync(d_ws, 0, 256, stream);

    gate_kernel<<<N_TOK / 4, 256, 0, stream>>>(x, gw, gb, counts, importance, sel, selw);

    if (ws_size >= NEED) {
        ushort_t* hbuf = (ushort_t*)(ws + HB_OFF);
        plan_kernel<<<1, 64, 0, stream>>>(counts, importance, cursors, offs, total_rows,
                                          row_token, row_wt, out + (size_t)N_TOK * DIM, 128);
        scatter_kernel<<<N_TOK / 256, 256, 0, stream>>>(sel, selw, cursors, offs, row_token, row_wt);
        cvt_x_kernel<<<(N_TOK * DIM) / 2048, 256, 0, stream>>>(x, xb);
        // W1^T (+ shared as z==8) -> wtbuf: [HID][DIM] bf16 per expert
        transpose_bf16<<<dim3(HID / 64, DIM / 64, 9), 256, 0, stream>>>(w1, sw1, wtbuf, DIM, HID);
        ffn1_mfma<<<dim3(HID / 128, ROW_CAP128 / 128), 256, 0, stream>>>(
            xb, wtbuf, b1, sb1, offs, total_rows, row_token, hbuf);
        // W2^T (+ shared as z==8) -> wtbuf (reused): [DIM][HID] bf16 per expert
        transpose_bf16<<<dim3(DIM / 64, HID / 64, 9), 256, 0, stream>>>(w2, sw2, wtbuf, HID, DIM);
        ffn2_mfma<<<dim3(DIM / 128, ROW_CAP128 / 128), 256, 0, stream>>>(
            hbuf, wtbuf, b2, sb2, offs, total_rows, row_token, row_wt, out);
    } else {
        // fallback: round-1 fp32 path (needs ~105 MB)
        ushort_t* hbuf = (ushort_t*)(ws + 262144);
        plan_kernel<<<1, 64, 0, stream>>>(counts, importance, cursors, offs, total_rows,
                                          row_token, row_wt, out + (size_t)N_TOK * DIM, 64);
        scatter_kernel<<<N_TOK / 256, 256, 0, stream>>>(sel, selw, cursors, offs, row_token, row_wt);
        ffn1_kernel<<<dim3(ROW_CAP64 / 64, HID / 64), 256, 0, stream>>>(
            x, w1, b1, sw1, sb1, offs, total_rows, row_token, hbuf);
        ffn2_kernel<<<dim3(ROW_CAP64 / 64, DIM / 64), 256, 0, stream>>>(
            hbuf, w2, b2, sw2, sb2, offs, total_rows, row_token, row_wt, out);
    }
}

// Round 5
// 881.265 us; speedup vs baseline: 1.1023x; 1.1023x over previous
//
#include <hip/hip_runtime.h>
#include <hip/hip_bf16.h>

#define N_TOK 4096
#define DIM   1024
#define HID   4096
#define NE    8
#define ROW_CAP256 14080   // 256-aligned expert regions (<=9984) + 4096 shared
#define ROW_CAP128 13312   // 128-aligned fallback
#define ROW_CAP64  12800   // fp32 fallback path (64-aligned)

typedef unsigned short ushort_t;
typedef short bf16x8 __attribute__((ext_vector_type(8)));
typedef float f32x4 __attribute__((ext_vector_type(4)));

// ---------- helpers ----------
__device__ __forceinline__ ushort_t f2bf(float f) {
    unsigned int u = __float_as_uint(f);
    u += 0x7fffu + ((u >> 16) & 1u);          // round-to-nearest-even
    return (ushort_t)(u >> 16);
}
__device__ __forceinline__ float bf2f(ushort_t u) {
    return __uint_as_float(((unsigned int)u) << 16);
}
__device__ __forceinline__ float gelu_f(float v) {
    return 0.5f * v * (1.0f + erff(v * 0.70710678118654752f));
}
// exec-barrier without vmcnt drain (prefetch loads stay in flight)
__device__ __forceinline__ void barrier_novm() {
    __builtin_amdgcn_s_waitcnt(0xC07F);   // lgkmcnt(0) only
    __builtin_amdgcn_s_barrier();
}
__device__ __forceinline__ void fma4x4(const float4& a, const float4& b, float acc[4][4]) {
    acc[0][0] = fmaf(a.x, b.x, acc[0][0]); acc[0][1] = fmaf(a.x, b.y, acc[0][1]);
    acc[0][2] = fmaf(a.x, b.z, acc[0][2]); acc[0][3] = fmaf(a.x, b.w, acc[0][3]);
    acc[1][0] = fmaf(a.y, b.x, acc[1][0]); acc[1][1] = fmaf(a.y, b.y, acc[1][1]);
    acc[1][2] = fmaf(a.y, b.z, acc[1][2]); acc[1][3] = fmaf(a.y, b.w, acc[1][3]);
    acc[2][0] = fmaf(a.z, b.x, acc[2][0]); acc[2][1] = fmaf(a.z, b.y, acc[2][1]);
    acc[2][2] = fmaf(a.z, b.z, acc[2][2]); acc[2][3] = fmaf(a.z, b.w, acc[2][3]);
    acc[3][0] = fmaf(a.w, b.x, acc[3][0]); acc[3][1] = fmaf(a.w, b.y, acc[3][1]);
    acc[3][2] = fmaf(a.w, b.z, acc[3][2]); acc[3][3] = fmaf(a.w, b.w, acc[3][3]);
}

// ---------- gating ----------
__global__ __launch_bounds__(256) void gate_kernel(
    const float* __restrict__ x, const float* __restrict__ gw, const float* __restrict__ gb,
    int* __restrict__ counts, float* __restrict__ importance,
    int* __restrict__ sel, float* __restrict__ selw)
{
    __shared__ float s_imp[NE];
    __shared__ int   s_cnt[NE];
    int tid = threadIdx.x;
    if (tid < NE) { s_imp[tid] = 0.f; s_cnt[tid] = 0; }
    __syncthreads();

    int wave = tid >> 6, lane = tid & 63;
    int n = blockIdx.x * 4 + wave;

    float acc[NE];
#pragma unroll
    for (int e = 0; e < NE; ++e) acc[e] = 0.f;

    const float* xr = x + (size_t)n * DIM;
    for (int it = 0; it < DIM / 64; ++it) {
        int d = it * 64 + lane;
        float xv = xr[d];
        const float4* g = (const float4*)(gw + (size_t)d * NE);
        float4 g0 = g[0], g1 = g[1];
        acc[0] = fmaf(xv, g0.x, acc[0]); acc[1] = fmaf(xv, g0.y, acc[1]);
        acc[2] = fmaf(xv, g0.z, acc[2]); acc[3] = fmaf(xv, g0.w, acc[3]);
        acc[4] = fmaf(xv, g1.x, acc[4]); acc[5] = fmaf(xv, g1.y, acc[5]);
        acc[6] = fmaf(xv, g1.z, acc[6]); acc[7] = fmaf(xv, g1.w, acc[7]);
    }
#pragma unroll
    for (int off = 32; off > 0; off >>= 1) {
#pragma unroll
        for (int e = 0; e < NE; ++e) acc[e] += __shfl_down(acc[e], off, 64);
    }

    if (lane == 0) {
        float lg[NE], p[NE];
        float mx = -1e30f;
#pragma unroll
        for (int e = 0; e < NE; ++e) { lg[e] = acc[e] + gb[e]; mx = fmaxf(mx, lg[e]); }
        float se = 0.f;
#pragma unroll
        for (int e = 0; e < NE; ++e) { p[e] = expf(lg[e] - mx); se += p[e]; }
        float inv = 1.f / se;
#pragma unroll
        for (int e = 0; e < NE; ++e) atomicAdd(&s_imp[e], p[e] * inv);
        int i1 = 0;
#pragma unroll
        for (int e = 1; e < NE; ++e) if (lg[e] > lg[i1]) i1 = e;
        int i2 = -1;
#pragma unroll
        for (int e = 0; e < NE; ++e) if (e != i1 && (i2 < 0 || lg[e] > lg[i2])) i2 = e;
        float t = expf(lg[i2] - lg[i1]);
        float wA = 1.f / (1.f + t), wB = t / (1.f + t);
        sel[n * 2] = i1; sel[n * 2 + 1] = i2;
        selw[n * 2] = wA; selw[n * 2 + 1] = wB;
        atomicAdd(&s_cnt[i1], 1); atomicAdd(&s_cnt[i2], 1);
    }
    __syncthreads();
    if (tid < NE) {
        atomicAdd(&importance[tid], s_imp[tid]);
        atomicAdd(&counts[tid], s_cnt[tid]);
    }
}

// ---------- plan ----------
__global__ void plan_kernel(
    const int* __restrict__ counts, const float* __restrict__ importance,
    int* __restrict__ cursors, int* __restrict__ offs, int* __restrict__ total_rows,
    int* __restrict__ row_token, float* __restrict__ row_wt, float* __restrict__ out_aux,
    int al)
{
    __shared__ int s_offs[NE + 1], s_cnt[NE];
    if (threadIdx.x == 0) {
        int o = 0;
        for (int e = 0; e < NE; ++e) {
            s_cnt[e] = counts[e];
            s_offs[e] = o;
            cursors[e] = o;
            o += (s_cnt[e] + al - 1) & ~(al - 1);
        }
        s_offs[NE] = o;
        for (int e = 0; e <= NE; ++e) offs[e] = s_offs[e];
        *total_rows = o + N_TOK;
        float is = 1e-8f, ls = 1e-8f;
        for (int e = 0; e < NE; ++e) { is += importance[e]; ls += (float)s_cnt[e]; }
        float aux = 0.f;
        for (int e = 0; e < NE; ++e) {
            float d = importance[e] / is - (float)s_cnt[e] / ls;
            aux += d * d;
        }
        *out_aux = aux;
    }
    __syncthreads();
    for (int e = 0; e < NE; ++e) {
        int st = s_offs[e] + s_cnt[e], en = s_offs[e + 1];
        for (int i = st + (int)threadIdx.x; i < en; i += (int)blockDim.x) {
            row_token[i] = -1; row_wt[i] = 0.f;
        }
    }
}

// ---------- scatter ----------
__global__ __launch_bounds__(256) void scatter_kernel(
    const int* __restrict__ sel, const float* __restrict__ selw,
    int* __restrict__ cursors, const int* __restrict__ offs,
    int* __restrict__ row_token, float* __restrict__ row_wt)
{
    int n = blockIdx.x * 256 + threadIdx.x;
#pragma unroll
    for (int k = 0; k < 2; ++k) {
        int e = sel[n * 2 + k];
        int pos = atomicAdd(&cursors[e], 1);
        row_token[pos] = n;
        row_wt[pos] = selw[n * 2 + k];
    }
    int off8 = offs[NE];
    row_token[off8 + n] = n;
    row_wt[off8 + n] = 1.0f;
}

// ---------- fp32 x -> bf16 ----------
__global__ __launch_bounds__(256) void cvt_x_kernel(
    const float* __restrict__ x, ushort_t* __restrict__ xb)
{
    int i = (blockIdx.x * 256 + threadIdx.x) * 8;
    float4 a = *(const float4*)(x + i);
    float4 b = *(const float4*)(x + i + 4);
    uint4 o;
    o.x = ((unsigned)f2bf(a.y) << 16) | f2bf(a.x);
    o.y = ((unsigned)f2bf(a.w) << 16) | f2bf(a.z);
    o.z = ((unsigned)f2bf(b.y) << 16) | f2bf(b.x);
    o.w = ((unsigned)f2bf(b.w) << 16) | f2bf(b.z);
    *(uint4*)(xb + i) = o;
}

// ---------- transpose+convert: src [K][N] fp32 -> dst [N][K] bf16 ----------
__global__ __launch_bounds__(256) void transpose_bf16(
    const float* __restrict__ src, const float* __restrict__ srcS,
    ushort_t* __restrict__ dst, int K, int N)
{
    __shared__ ushort_t T[64][80];
    const float* s = (blockIdx.z < 8) ? (src + (size_t)blockIdx.z * K * N) : srcS;
    dst += (size_t)blockIdx.z * K * N;
    int n0 = blockIdx.x * 64, k0 = blockIdx.y * 64;
    int t = threadIdx.x;
    int cq = (t & 15) * 4;
    int kr = t >> 4;
#pragma unroll
    for (int rI = 0; rI < 4; ++rI) {
        int k = kr + rI * 16;
        float4 v = *(const float4*)(s + (size_t)(k0 + k) * N + n0 + cq);
        T[cq + 0][k] = f2bf(v.x);
        T[cq + 1][k] = f2bf(v.y);
        T[cq + 2][k] = f2bf(v.z);
        T[cq + 3][k] = f2bf(v.w);
    }
    __syncthreads();
    int nr = t >> 2;
    int kq = (t & 3) * 16;
    uint4 o0 = *(const uint4*)&T[nr][kq];
    uint4 o1 = *(const uint4*)&T[nr][kq + 8];
    ushort_t* dp = dst + (size_t)(n0 + nr) * K + k0 + kq;
    *(uint4*)dp = o0;
    *(uint4*)(dp + 8) = o1;
}

// ---------- templated MFMA grouped GEMM kernels ----------
// Block tile: TM = WM*MF*16 rows, TN = WN*NF*16 cols, WM*WN waves (64 lanes each).
// Requires MF == 2*WN and NF == 2*WM so each wave stages exactly 2 A-slabs + 2 B-slabs.
// K-loop: register-prefetch pipeline; barrier-2 without vmcnt drain.

template<int WM, int WN, int MF, int NF>
__global__ __launch_bounds__(WM*WN*64, 2) void ffn1_mfma_t(
    const ushort_t* __restrict__ xb, const ushort_t* __restrict__ wtbuf,
    const float* __restrict__ b1, const float* __restrict__ sb1,
    const int* __restrict__ offs, const int* __restrict__ total_rows,
    const int* __restrict__ row_token, ushort_t* __restrict__ hbuf)
{
    constexpr int TM = WM * MF * 16, TN = WN * NF * 16;
    const int row0 = blockIdx.y * TM;
    if (row0 >= *total_rows) return;
    const int col0 = blockIdx.x * TN;

    int e = 0;
#pragma unroll
    for (int i = 0; i < NE; ++i) e += (row0 >= offs[i + 1]) ? 1 : 0;
    const ushort_t* W = wtbuf + (size_t)e * (HID * DIM);       // [HID][DIM] bf16
    const float* Bv = (e < NE) ? (b1 + (size_t)e * HID) : sb1;

    __shared__ ushort_t As[TM * 32];   // TM/16 slabs x 512 (lane-ordered 16B/lane)
    __shared__ ushort_t Bs[TN * 32];

    const int tid = threadIdx.x;
    const int lane = tid & 63;
    const int w = tid >> 6;
    const int wm = w % WM, wn = w / WM;
    const int lm = lane & 15, lk = lane >> 4;

    const int sS = 2 * w;
    int r0 = row0 + (sS + 0) * 16 + lm;
    int r1 = row0 + (sS + 1) * 16 + lm;
    int t0 = row_token[r0]; if (t0 < 0) t0 = 0;
    int t1 = row_token[r1]; if (t1 < 0) t1 = 0;
    const ushort_t* gA0 = xb + (size_t)t0 * DIM + lk * 8;
    const ushort_t* gA1 = xb + (size_t)t1 * DIM + lk * 8;
    const ushort_t* gB0 = W + (size_t)(col0 + (sS + 0) * 16 + lm) * DIM + lk * 8;
    const ushort_t* gB1 = W + (size_t)(col0 + (sS + 1) * 16 + lm) * DIM + lk * 8;
    ushort_t* lA0 = &As[(sS + 0) * 512 + lane * 8];
    ushort_t* lA1 = &As[(sS + 1) * 512 + lane * 8];
    ushort_t* lB0 = &Bs[(sS + 0) * 512 + lane * 8];
    ushort_t* lB1 = &Bs[(sS + 1) * 512 + lane * 8];

    f32x4 zero = {0.f, 0.f, 0.f, 0.f};
    f32x4 acc[MF][NF];
#pragma unroll
    for (int i = 0; i < MF; ++i)
#pragma unroll
        for (int j = 0; j < NF; ++j) acc[i][j] = zero;

    const bf16x8* Af = (const bf16x8*)As;
    const bf16x8* Bf = (const bf16x8*)Bs;

    uint4 rA0 = *(const uint4*)(gA0);
    uint4 rA1 = *(const uint4*)(gA1);
    uint4 rB0 = *(const uint4*)(gB0);
    uint4 rB1 = *(const uint4*)(gB1);

    for (int k0 = 0; k0 < DIM; k0 += 32) {
        *(uint4*)lA0 = rA0;
        *(uint4*)lA1 = rA1;
        *(uint4*)lB0 = rB0;
        *(uint4*)lB1 = rB1;
        __syncthreads();
        if (k0 + 32 < DIM) {
            rA0 = *(const uint4*)(gA0 + k0 + 32);
            rA1 = *(const uint4*)(gA1 + k0 + 32);
            rB0 = *(const uint4*)(gB0 + k0 + 32);
            rB1 = *(const uint4*)(gB1 + k0 + 32);
        }
        bf16x8 a[MF], b[NF];
#pragma unroll
        for (int i = 0; i < MF; ++i) a[i] = Af[(wm * MF + i) * 64 + lane];
#pragma unroll
        for (int j = 0; j < NF; ++j) b[j] = Bf[(wn * NF + j) * 64 + lane];
#pragma unroll
        for (int i = 0; i < MF; ++i)
#pragma unroll
            for (int j = 0; j < NF; ++j)
                acc[i][j] = __builtin_amdgcn_mfma_f32_16x16x32_bf16(a[i], b[j], acc[i][j], 0, 0, 0);
        barrier_novm();
    }

#pragma unroll
    for (int j = 0; j < NF; ++j) {
        int C = col0 + (wn * NF + j) * 16 + lm;
        float bj = Bv[C];
#pragma unroll
        for (int i = 0; i < MF; ++i) {
            int Rb = row0 + (wm * MF + i) * 16 + lk * 4;
#pragma unroll
            for (int r = 0; r < 4; ++r) {
                float v = gelu_f(acc[i][j][r] + bj);
                hbuf[(size_t)(Rb + r) * HID + C] = f2bf(v);
            }
        }
    }
}

template<int WM, int WN, int MF, int NF>
__global__ __launch_bounds__(WM*WN*64, 2) void ffn2_mfma_t(
    const ushort_t* __restrict__ hbuf, const ushort_t* __restrict__ wtbuf,
    const float* __restrict__ b2, const float* __restrict__ sb2,
    const int* __restrict__ offs, const int* __restrict__ total_rows,
    const int* __restrict__ row_token, const float* __restrict__ row_wt,
    float* __restrict__ out)
{
    constexpr int TM = WM * MF * 16, TN = WN * NF * 16;
    const int row0 = blockIdx.y * TM;
    if (row0 >= *total_rows) return;
    const int col0 = blockIdx.x * TN;

    int e = 0;
#pragma unroll
    for (int i = 0; i < NE; ++i) e += (row0 >= offs[i + 1]) ? 1 : 0;
    const ushort_t* W = wtbuf + (size_t)e * (HID * DIM);       // [DIM][HID] bf16
    const float* Bv = (e < NE) ? (b2 + (size_t)e * DIM) : sb2;

    __shared__ ushort_t As[TM * 32];
    __shared__ ushort_t Bs[TN * 32];
    __shared__ int   s_tok[TM];
    __shared__ float s_wt[TM];

    const int tid = threadIdx.x;
    if (tid < TM) { s_tok[tid] = row_token[row0 + tid]; s_wt[tid] = row_wt[row0 + tid]; }

    const int lane = tid & 63;
    const int w = tid >> 6;
    const int wm = w % WM, wn = w / WM;
    const int lm = lane & 15, lk = lane >> 4;

    const int sS = 2 * w;
    const ushort_t* gA0 = hbuf + (size_t)(row0 + (sS + 0) * 16 + lm) * HID + lk * 8;
    const ushort_t* gA1 = hbuf + (size_t)(row0 + (sS + 1) * 16 + lm) * HID + lk * 8;
    const ushort_t* gB0 = W + (size_t)(col0 + (sS + 0) * 16 + lm) * HID + lk * 8;
    const ushort_t* gB1 = W + (size_t)(col0 + (sS + 1) * 16 + lm) * HID + lk * 8;
    ushort_t* lA0 = &As[(sS + 0) * 512 + lane * 8];
    ushort_t* lA1 = &As[(sS + 1) * 512 + lane * 8];
    ushort_t* lB0 = &Bs[(sS + 0) * 512 + lane * 8];
    ushort_t* lB1 = &Bs[(sS + 1) * 512 + lane * 8];

    f32x4 zero = {0.f, 0.f, 0.f, 0.f};
    f32x4 acc[MF][NF];
#pragma unroll
    for (int i = 0; i < MF; ++i)
#pragma unroll
        for (int j = 0; j < NF; ++j) acc[i][j] = zero;

    const bf16x8* Af = (const bf16x8*)As;
    const bf16x8* Bf = (const bf16x8*)Bs;

    uint4 rA0 = *(const uint4*)(gA0);
    uint4 rA1 = *(const uint4*)(gA1);
    uint4 rB0 = *(const uint4*)(gB0);
    uint4 rB1 = *(const uint4*)(gB1);

    for (int k0 = 0; k0 < HID; k0 += 32) {
        *(uint4*)lA0 = rA0;
        *(uint4*)lA1 = rA1;
        *(uint4*)lB0 = rB0;
        *(uint4*)lB1 = rB1;
        __syncthreads();
        if (k0 + 32 < HID) {
            rA0 = *(const uint4*)(gA0 + k0 + 32);
            rA1 = *(const uint4*)(gA1 + k0 + 32);
            rB0 = *(const uint4*)(gB0 + k0 + 32);
            rB1 = *(const uint4*)(gB1 + k0 + 32);
        }
        bf16x8 a[MF], b[NF];
#pragma unroll
        for (int i = 0; i < MF; ++i) a[i] = Af[(wm * MF + i) * 64 + lane];
#pragma unroll
        for (int j = 0; j < NF; ++j) b[j] = Bf[(wn * NF + j) * 64 + lane];
#pragma unroll
        for (int i = 0; i < MF; ++i)
#pragma unroll
            for (int j = 0; j < NF; ++j)
                acc[i][j] = __builtin_amdgcn_mfma_f32_16x16x32_bf16(a[i], b[j], acc[i][j], 0, 0, 0);
        barrier_novm();
    }

#pragma unroll
    for (int j = 0; j < NF; ++j) {
        int C = col0 + (wn * NF + j) * 16 + lm;
        float bj = Bv[C];
#pragma unroll
        for (int i = 0; i < MF; ++i) {
            int rb = (wm * MF + i) * 16 + lk * 4;
#pragma unroll
            for (int r = 0; r < 4; ++r) {
                int tok = s_tok[rb + r];
                if (tok < 0) continue;
                float v = s_wt[rb + r] * (acc[i][j][r] + bj);
                atomicAdd(&out[(size_t)tok * DIM + C], v);
            }
        }
    }
}

// ---------- fallback fp32 FFN kernels (used only if ws too small) ----------
__global__ __launch_bounds__(256) void ffn1_kernel(
    const float* __restrict__ x, const float* __restrict__ w1, const float* __restrict__ b1,
    const float* __restrict__ sw1, const float* __restrict__ sb1,
    const int* __restrict__ offs, const int* __restrict__ total_rows,
    const int* __restrict__ row_token, ushort_t* __restrict__ hbuf)
{
    int row0 = blockIdx.x * 64;
    if (row0 >= *total_rows) return;
    int col0 = blockIdx.y * 64;
    int e = 0;
#pragma unroll
    for (int i = 1; i <= NE; ++i) if (row0 >= offs[i]) e = i;
    const float* W = (e < NE) ? w1 + (size_t)e * DIM * HID : sw1;
    const float* B = (e < NE) ? b1 + (size_t)e * HID : sb1;

    __shared__ float As_[16][68];
    __shared__ float Bs_[16][64];
    __shared__ int toks[64];
    int tid = threadIdx.x;
    if (tid < 64) toks[tid] = row_token[row0 + tid];
    __syncthreads();

    int am = tid >> 2, ak = (tid & 3) << 2;
    int bkr = tid >> 4, bn = (tid & 15) << 2;
    int tx = tid & 15, ty = tid >> 4;
    int tok = toks[am];
    const float* ap = x + (size_t)(tok >= 0 ? tok : 0) * DIM + ak;
    const float* bp = W + (size_t)bkr * HID + col0 + bn;

    float acc[4][4] = {};
    for (int k0 = 0; k0 < DIM; k0 += 16) {
        float4 av = make_float4(0.f, 0.f, 0.f, 0.f);
        if (tok >= 0) av = *(const float4*)(ap + k0);
        float4 bv = *(const float4*)(bp + (size_t)k0 * HID);
        As_[ak + 0][am] = av.x; As_[ak + 1][am] = av.y;
        As_[ak + 2][am] = av.z; As_[ak + 3][am] = av.w;
        *(float4*)&Bs_[bkr][bn] = bv;
        __syncthreads();
#pragma unroll
        for (int kk = 0; kk < 16; ++kk) {
            float4 a = *(const float4*)&As_[kk][ty * 4];
            float4 b = *(const float4*)&Bs_[kk][tx * 4];
            fma4x4(a, b, acc);
        }
        __syncthreads();
    }
    float4 bb = *(const float4*)(B + col0 + tx * 4);
    ushort_t* hp = hbuf + (size_t)(row0 + ty * 4) * HID + col0 + tx * 4;
#pragma unroll
    for (int r = 0; r < 4; ++r) {
        ushort4 pk;
        pk.x = f2bf(gelu_f(acc[r][0] + bb.x));
        pk.y = f2bf(gelu_f(acc[r][1] + bb.y));
        pk.z = f2bf(gelu_f(acc[r][2] + bb.z));
        pk.w = f2bf(gelu_f(acc[r][3] + bb.w));
        *(ushort4*)(hp + (size_t)r * HID) = pk;
    }
}

__global__ __launch_bounds__(256) void ffn2_kernel(
    const ushort_t* __restrict__ hbuf,
    const float* __restrict__ w2, const float* __restrict__ b2,
    const float* __restrict__ sw2, const float* __restrict__ sb2,
    const int* __restrict__ offs, const int* __restrict__ total_rows,
    const int* __restrict__ row_token, const float* __restrict__ row_wt,
    float* __restrict__ out)
{
    int row0 = blockIdx.x * 64;
    if (row0 >= *total_rows) return;
    int col0 = blockIdx.y * 64;
    int e = 0;
#pragma unroll
    for (int i = 1; i <= NE; ++i) if (row0 >= offs[i]) e = i;
    const float* W = (e < NE) ? w2 + (size_t)e * HID * DIM : sw2;
    const float* B = (e < NE) ? b2 + (size_t)e * DIM : sb2;

    __shared__ float As_[16][68];
    __shared__ float Bs_[16][64];
    __shared__ int toks[64];
    __shared__ float wts[64];
    int tid = threadIdx.x;
    if (tid < 64) { toks[tid] = row_token[row0 + tid]; wts[tid] = row_wt[row0 + tid]; }
    __syncthreads();

    int am = tid >> 2, ak = (tid & 3) << 2;
    int bkr = tid >> 4, bn = (tid & 15) << 2;
    int tx = tid & 15, ty = tid >> 4;
    const ushort_t* ap = hbuf + (size_t)(row0 + am) * HID + ak;
    const float* bp = W + (size_t)bkr * DIM + col0 + bn;

    float acc[4][4] = {};
    for (int k0 = 0; k0 < HID; k0 += 16) {
        ushort4 hv = *(const ushort4*)(ap + k0);
        float4 bv = *(const float4*)(bp + (size_t)k0 * DIM);
        As_[ak + 0][am] = bf2f(hv.x); As_[ak + 1][am] = bf2f(hv.y);
        As_[ak + 2][am] = bf2f(hv.z); As_[ak + 3][am] = bf2f(hv.w);
        *(float4*)&Bs_[bkr][bn] = bv;
        __syncthreads();
#pragma unroll
        for (int kk = 0; kk < 16; ++kk) {
            float4 a = *(const float4*)&As_[kk][ty * 4];
            float4 b = *(const float4*)&Bs_[kk][tx * 4];
            fma4x4(a, b, acc);
        }
        __syncthreads();
    }
    float4 bb = *(const float4*)(B + col0 + tx * 4);
#pragma unroll
    for (int r = 0; r < 4; ++r) {
        int rr = ty * 4 + r;
        int tok = toks[rr];
        if (tok < 0) continue;
        float w = wts[rr];
        float* op = out + (size_t)tok * DIM + col0 + tx * 4;
        atomicAdd(&op[0], w * (acc[r][0] + bb.x));
        atomicAdd(&op[1], w * (acc[r][1] + bb.y));
        atomicAdd(&op[2], w * (acc[r][2] + bb.z));
        atomicAdd(&op[3], w * (acc[r][3] + bb.w));
    }
}

// ---------- launch ----------
extern "C" void kernel_launch(void* const* d_in, const int* in_sizes, int n_in,
                              void* d_out, int out_size, void* d_ws, size_t ws_size,
                              hipStream_t stream)
{
    const float* x   = (const float*)d_in[0];
    const float* gw  = (const float*)d_in[1];
    const float* gb  = (const float*)d_in[2];
    const float* w1  = (const float*)d_in[3];
    const float* b1  = (const float*)d_in[4];
    const float* w2  = (const float*)d_in[5];
    const float* b2  = (const float*)d_in[6];
    const float* sw1 = (const float*)d_in[7];
    const float* sb1 = (const float*)d_in[8];
    const float* sw2 = (const float*)d_in[9];
    const float* sb2 = (const float*)d_in[10];
    float* out = (float*)d_out;

    char* ws = (char*)d_ws;
    int*   counts     = (int*)(ws + 0);
    int*   cursors    = (int*)(ws + 32);
    int*   offs       = (int*)(ws + 64);
    int*   total_rows = (int*)(ws + 100);
    float* importance = (float*)(ws + 128);
    int*   sel        = (int*)(ws + 256);      // [N*2] ints
    float* selw       = (float*)(ws + 33024);  // [N*2] floats
    int*   row_token  = (int*)(ws + 65792);    // [<=14080] ints (56320 B)
    float* row_wt     = (float*)(ws + 122112); // [<=14080] floats

    const size_t XB_OFF  = 262144;
    const size_t WT_OFF  = XB_OFF + (size_t)N_TOK * DIM * 2;                // 8.39 MB xb
    const size_t HB_OFF  = WT_OFF + (size_t)9 * HID * DIM * 2;              // 75.5 MB weights
    const size_t NEED256 = HB_OFF + (size_t)ROW_CAP256 * HID * 2;           // ~199.5 MB
    const size_t NEED128 = HB_OFF + (size_t)ROW_CAP128 * HID * 2;           // ~193.2 MB
    ushort_t* xb    = (ushort_t*)(ws + XB_OFF);
    ushort_t* wtbuf = (ushort_t*)(ws + WT_OFF);
    ushort_t* hbuf  = (ushort_t*)(ws + HB_OFF);

    hipMemsetAsync(d_out, 0, (size_t)out_size * sizeof(float), stream);
    hipMemsetAsync(d_ws, 0, 256, stream);

    gate_kernel<<<N_TOK / 4, 256, 0, stream>>>(x, gw, gb, counts, importance, sel, selw);

    if (ws_size >= NEED256) {
        // 256x256 tiles, 512 threads: halves L2/L3 traffic vs 128-tile
        plan_kernel<<<1, 64, 0, stream>>>(counts, importance, cursors, offs, total_rows,
                                          row_token, row_wt, out + (size_t)N_TOK * DIM, 256);
        scatter_kernel<<<N_TOK / 256, 256, 0, stream>>>(sel, selw, cursors, offs, row_token, row_wt);
        cvt_x_kernel<<<(N_TOK * DIM) / 2048, 256, 0, stream>>>(x, xb);
        transpose_bf16<<<dim3(HID / 64, DIM / 64, 9), 256, 0, stream>>>(w1, sw1, wtbuf, DIM, HID);
        ffn1_mfma_t<2, 4, 8, 4><<<dim3(HID / 256, ROW_CAP256 / 256), 512, 0, stream>>>(
            xb, wtbuf, b1, sb1, offs, total_rows, row_token, hbuf);
        transpose_bf16<<<dim3(DIM / 64, HID / 64, 9), 256, 0, stream>>>(w2, sw2, wtbuf, HID, DIM);
        ffn2_mfma_t<2, 4, 8, 4><<<dim3(DIM / 256, ROW_CAP256 / 256), 512, 0, stream>>>(
            hbuf, wtbuf, b2, sb2, offs, total_rows, row_token, row_wt, out);
    } else if (ws_size >= NEED128) {
        // 128x128 tiles, 256 threads (round-4 behavior)
        plan_kernel<<<1, 64, 0, stream>>>(counts, importance, cursors, offs, total_rows,
                                          row_token, row_wt, out + (size_t)N_TOK * DIM, 128);
        scatter_kernel<<<N_TOK / 256, 256, 0, stream>>>(sel, selw, cursors, offs, row_token, row_wt);
        cvt_x_kernel<<<(N_TOK * DIM) / 2048, 256, 0, stream>>>(x, xb);
        transpose_bf16<<<dim3(HID / 64, DIM / 64, 9), 256, 0, stream>>>(w1, sw1, wtbuf, DIM, HID);
        ffn1_mfma_t<2, 2, 4, 4><<<dim3(HID / 128, ROW_CAP128 / 128), 256, 0, stream>>>(
            xb, wtbuf, b1, sb1, offs, total_rows, row_token, hbuf);
        transpose_bf16<<<dim3(DIM / 64, HID / 64, 9), 256, 0, stream>>>(w2, sw2, wtbuf, HID, DIM);
        ffn2_mfma_t<2, 2, 4, 4><<<dim3(DIM / 128, ROW_CAP128 / 128), 256, 0, stream>>>(
            hbuf, wtbuf, b2, sb2, offs, total_rows, row_token, row_wt, out);
    } else {
        // fp32 fallback
        ushort_t* hb = (ushort_t*)(ws + XB_OFF);
        plan_kernel<<<1, 64, 0, stream>>>(counts, importance, cursors, offs, total_rows,
                                          row_token, row_wt, out + (size_t)N_TOK * DIM, 64);
        scatter_kernel<<<N_TOK / 256, 256, 0, stream>>>(sel, selw, cursors, offs, row_token, row_wt);
        ffn1_kernel<<<dim3(ROW_CAP64 / 64, HID / 64), 256, 0, stream>>>(
            x, w1, b1, sw1, sb1, offs, total_rows, row_token, hb);
        ffn2_kernel<<<dim3(ROW_CAP64 / 64, DIM / 64), 256, 0, stream>>>(
            hb, w2, b2, sw2, sb2, offs, total_rows, row_token, row_wt, out);
    }
}